// Round 1
// baseline (779.674 us; speedup 1.0000x reference)
//
#include <hip/hip_runtime.h>
#include <math.h>

// Problem constants
#define LL    65536
#define NB    32
#define TSUB  128                 // output timesteps per thread
#define TBLK  (16 * TSUB)         // timesteps per block (16 j-chunks)
#define NTILES (LL / TBLK)        // 32 tiles along time
#define WARM  192                 // warm-up steps (alpha^192 ~ 1e-28; co-spike resync is exact)
#define NI    (NB * 16 * LL)      // elements per big output (33,554,432)

__device__ __forceinline__ double softplus_d(double x) {
  return (x > 0.0) ? (x + log1p(exp(-x))) : log1p(exp(x));
}

// Block: 256 threads = 16 channels (c16 = branch*8 + c) x 16 time-chunks (j).
// Grid: (NTILES, B). Each thread runs a serial LIF scan over WARM+TSUB steps,
// recomputing the K=8 causal conv from a sliding register window of x.
__global__ __launch_bounds__(256, 4)
void snn_fused(const float* __restrict__ x,
               const float* __restrict__ wa, const float* __restrict__ wb,
               const float* __restrict__ rta, const float* __restrict__ rtb,
               const float* __restrict__ rga, const float* __restrict__ rgb,
               float* __restrict__ out)
{
  const int tid  = threadIdx.x;
  const int c16  = tid & 15;      // channel within concat order (0..7 = a, 8..15 = b)
  const int j    = tid >> 4;      // time-chunk within block
  const int tile = blockIdx.x;
  const int b    = blockIdx.y;
  const int br   = c16 >> 3;
  const int c    = c16 & 7;

  // --- per-thread constants, computed in double then rounded to f32 ---
  const float* wrow = (br ? wb : wa) + c * 8;
  double ss = 0.0;
  #pragma unroll
  for (int k = 0; k < 8; ++k) { double wv = (double)wrow[k]; ss += wv * wv; }
  double nrm = sqrt(ss); if (nrm < 1e-8) nrm = 1e-8;
  const float w0 = (float)((double)wrow[0] / nrm);
  const float w1 = (float)((double)wrow[1] / nrm);
  const float w2 = (float)((double)wrow[2] / nrm);
  const float w3 = (float)((double)wrow[3] / nrm);
  const float w4 = (float)((double)wrow[4] / nrm);
  const float w5 = (float)((double)wrow[5] / nrm);
  const float w6 = (float)((double)wrow[6] / nrm);
  const float w7 = (float)((double)wrow[7] / nrm);

  const float rt    = br ? rtb[c] : rta[c];
  const float alpha = (float)exp(-1.0 / (softplus_d((double)rt) + 1e-4));
  const float oma   = 1.0f - alpha;
  const float g     = (float)(softplus_d((double)(br ? rgb[0] : rga[0])) + 1e-4);

  const int t_out = tile * TBLK + j * TSUB;
  int t0 = t_out - WARM; if (t0 < 0) t0 = 0;   // clamped start is EXACT (v0=0 at t=0)

  const float* xrow = x + (size_t)(b * 2 + br) * LL;

  // sliding window: x[t-7..t-1] pre-scaled by X_SCALE=20
  float m7, m6, m5, m4, m3, m2, m1;
  {
    const int base = t0 - 7;
    m7 = (base + 0 >= 0) ? 20.0f * xrow[base + 0] : 0.0f;
    m6 = (base + 1 >= 0) ? 20.0f * xrow[base + 1] : 0.0f;
    m5 = (base + 2 >= 0) ? 20.0f * xrow[base + 2] : 0.0f;
    m4 = (base + 3 >= 0) ? 20.0f * xrow[base + 3] : 0.0f;
    m3 = (base + 4 >= 0) ? 20.0f * xrow[base + 4] : 0.0f;
    m2 = (base + 5 >= 0) ? 20.0f * xrow[base + 5] : 0.0f;
    m1 = (base + 6 >= 0) ? 20.0f * xrow[base + 6] : 0.0f;
  }
  float v = 0.0f;

  // one LIF step; cx = 20*x[t]; updates window + membrane state
  auto step = [&](float cx, float& Iv, float& zv, float& sv) {
    float acc = m7 * w0;
    acc = fmaf(m6, w1, acc);
    acc = fmaf(m5, w2, acc);
    acc = fmaf(m4, w3, acc);
    acc = fmaf(m3, w4, acc);
    acc = fmaf(m2, w5, acc);
    acc = fmaf(m1, w6, acc);
    acc = fmaf(cx, w7, acc);
    Iv = g * acc;
    float vpre = fmaf(alpha, v, oma * Iv);
    zv = 15.0f * (vpre - 0.25f);
    bool sp = vpre >= 0.25f;
    sv = sp ? 1.0f : 0.0f;
    v  = sp ? 0.0f : vpre;
    m7 = m6; m6 = m5; m5 = m4; m4 = m3; m3 = m2; m2 = m1; m1 = cx;
  };

  // --- warm-up (no stores) ---
  for (int t = t0; t < t_out; t += 4) {
    const float4 xv = *(const float4*)(xrow + t);
    float dI, dz, ds_;
    step(20.0f * xv.x, dI, dz, ds_);
    step(20.0f * xv.y, dI, dz, ds_);
    step(20.0f * xv.z, dI, dz, ds_);
    step(20.0f * xv.w, dI, dz, ds_);
  }

  float* outI = out + (size_t)(b * 16 + c16) * LL;
  float* outZ = outI + (size_t)NI;
  float* outS = outI + (size_t)2 * NI;
  float* outG = out + (size_t)3 * NI + (size_t)b * LL;

  // --- output region ---
  for (int t = t_out; t < t_out + TSUB; t += 4) {
    const float4 xv = *(const float4*)(xrow + t);
    float I0, I1, I2, I3, z0, z1, z2, z3, s0, s1, s2, s3;
    step(20.0f * xv.x, I0, z0, s0);
    step(20.0f * xv.y, I1, z1, s1);
    step(20.0f * xv.z, I2, z2, s2);
    step(20.0f * xv.w, I3, z3, s3);

    *(float4*)(outI + t) = make_float4(I0, I1, I2, I3);
    *(float4*)(outZ + t) = make_float4(z0, z1, z2, z3);
    *(float4*)(outS + t) = make_float4(s0, s1, s2, s3);

    // logits = max over the 16 channels: xor-shuffle reduce within 16-lane groups
    float g0 = z0, g1 = z1, g2 = z2, g3 = z3;
    #pragma unroll
    for (int msk = 1; msk < 16; msk <<= 1) {
      g0 = fmaxf(g0, __shfl_xor(g0, msk, 16));
      g1 = fmaxf(g1, __shfl_xor(g1, msk, 16));
      g2 = fmaxf(g2, __shfl_xor(g2, msk, 16));
      g3 = fmaxf(g3, __shfl_xor(g3, msk, 16));
    }
    if (c16 == 0) *(float4*)(outG + t) = make_float4(g0, g1, g2, g3);
  }
}

extern "C" void kernel_launch(void* const* d_in, const int* in_sizes, int n_in,
                              void* d_out, int out_size, void* d_ws, size_t ws_size,
                              hipStream_t stream) {
  const float* x   = (const float*)d_in[0];
  const float* wa  = (const float*)d_in[1];
  const float* wb  = (const float*)d_in[2];
  const float* rta = (const float*)d_in[3];
  const float* rtb = (const float*)d_in[4];
  const float* rga = (const float*)d_in[5];
  const float* rgb = (const float*)d_in[6];
  float* out = (float*)d_out;

  dim3 grid(NTILES, NB);
  hipLaunchKernelGGL(snn_fused, grid, dim3(256), 0, stream,
                     x, wa, wb, rta, rtb, rga, rgb, out);
}

// Round 2
// 580.144 us; speedup vs baseline: 1.3439x; 1.3439x over previous
//
#include <hip/hip_runtime.h>
#include <math.h>

// Problem constants
#define LL    65536
#define NB    32
#define TSUB  128                 // output timesteps per thread
#define TBLK  (16 * TSUB)         // timesteps per block (16 j-chunks)
#define NTILES (LL / TBLK)        // 32 tiles along time
#define WARM  192                 // warm-up steps (alpha^192 ~ 1e-28; co-spike resync is exact)
#define NI    (NB * 16 * LL)      // elements per big output (33,554,432)

__device__ __forceinline__ double softplus_d(double x) {
  return (x > 0.0) ? (x + log1p(exp(-x))) : log1p(exp(x));
}

// Block: 256 threads = 16 channels (c16 = branch*8 + c) x 16 time-chunks (j).
// Grid: (NTILES, B). Each thread runs a serial LIF scan over WARM+TSUB steps,
// recomputing the K=8 causal conv from a sliding register window of x.
// R1: 16-step register batching so each lane's 4 float4 stores complete a
// 64B line back-to-back -> L2 write-back evicts each line once, fully dirty.
__global__ __launch_bounds__(256, 4)
void snn_fused(const float* __restrict__ x,
               const float* __restrict__ wa, const float* __restrict__ wb,
               const float* __restrict__ rta, const float* __restrict__ rtb,
               const float* __restrict__ rga, const float* __restrict__ rgb,
               float* __restrict__ out)
{
  const int tid  = threadIdx.x;
  const int c16  = tid & 15;      // channel within concat order (0..7 = a, 8..15 = b)
  const int j    = tid >> 4;      // time-chunk within block
  const int tile = blockIdx.x;
  const int b    = blockIdx.y;
  const int br   = c16 >> 3;
  const int c    = c16 & 7;

  // --- per-thread constants, computed in double then rounded to f32 ---
  const float* wrow = (br ? wb : wa) + c * 8;
  double ss = 0.0;
  #pragma unroll
  for (int k = 0; k < 8; ++k) { double wv = (double)wrow[k]; ss += wv * wv; }
  double nrm = sqrt(ss); if (nrm < 1e-8) nrm = 1e-8;
  const float w0 = (float)((double)wrow[0] / nrm);
  const float w1 = (float)((double)wrow[1] / nrm);
  const float w2 = (float)((double)wrow[2] / nrm);
  const float w3 = (float)((double)wrow[3] / nrm);
  const float w4 = (float)((double)wrow[4] / nrm);
  const float w5 = (float)((double)wrow[5] / nrm);
  const float w6 = (float)((double)wrow[6] / nrm);
  const float w7 = (float)((double)wrow[7] / nrm);

  const float rt    = br ? rtb[c] : rta[c];
  const float alpha = (float)exp(-1.0 / (softplus_d((double)rt) + 1e-4));
  const float oma   = 1.0f - alpha;
  const float g     = (float)(softplus_d((double)(br ? rgb[0] : rga[0])) + 1e-4);

  const int t_out = tile * TBLK + j * TSUB;
  int t0 = t_out - WARM; if (t0 < 0) t0 = 0;   // clamped start is EXACT (v0=0 at t=0)

  const float* xrow = x + (size_t)(b * 2 + br) * LL;

  // sliding window: x[t-7..t-1] pre-scaled by X_SCALE=20
  float m7, m6, m5, m4, m3, m2, m1;
  {
    const int base = t0 - 7;
    m7 = (base + 0 >= 0) ? 20.0f * xrow[base + 0] : 0.0f;
    m6 = (base + 1 >= 0) ? 20.0f * xrow[base + 1] : 0.0f;
    m5 = (base + 2 >= 0) ? 20.0f * xrow[base + 2] : 0.0f;
    m4 = (base + 3 >= 0) ? 20.0f * xrow[base + 3] : 0.0f;
    m3 = (base + 4 >= 0) ? 20.0f * xrow[base + 4] : 0.0f;
    m2 = (base + 5 >= 0) ? 20.0f * xrow[base + 5] : 0.0f;
    m1 = (base + 6 >= 0) ? 20.0f * xrow[base + 6] : 0.0f;
  }
  float v = 0.0f;

  // one LIF step; cx = 20*x[t]; updates window + membrane state
  auto step = [&](float cx, float& Iv, float& zv, float& sv) {
    float acc = m7 * w0;
    acc = fmaf(m6, w1, acc);
    acc = fmaf(m5, w2, acc);
    acc = fmaf(m4, w3, acc);
    acc = fmaf(m3, w4, acc);
    acc = fmaf(m2, w5, acc);
    acc = fmaf(m1, w6, acc);
    acc = fmaf(cx, w7, acc);
    Iv = g * acc;
    float vpre = fmaf(alpha, v, oma * Iv);
    zv = 15.0f * (vpre - 0.25f);
    bool sp = vpre >= 0.25f;
    sv = sp ? 1.0f : 0.0f;
    v  = sp ? 0.0f : vpre;
    m7 = m6; m6 = m5; m5 = m4; m4 = m3; m3 = m2; m2 = m1; m1 = cx;
  };

  // --- warm-up (no stores) ---
  for (int t = t0; t < t_out; t += 4) {
    const float4 xv = *(const float4*)(xrow + t);
    float dI, dz, ds_;
    step(20.0f * xv.x, dI, dz, ds_);
    step(20.0f * xv.y, dI, dz, ds_);
    step(20.0f * xv.z, dI, dz, ds_);
    step(20.0f * xv.w, dI, dz, ds_);
  }

  float* outI = out + (size_t)(b * 16 + c16) * LL;
  float* outZ = outI + (size_t)NI;
  float* outS = outI + (size_t)2 * NI;
  float* outG = out + (size_t)3 * NI + (size_t)b * LL;

  // --- output region: 16-step batches; per batch each lane fills one full
  // 64B line per output with 4 back-to-back float4 stores ---
  for (int t = t_out; t < t_out + TSUB; t += 16) {
    float Ib[16], zb[16], sb[16];
    #pragma unroll
    for (int q = 0; q < 4; ++q) {
      const float4 xv = *(const float4*)(xrow + t + 4 * q);
      step(20.0f * xv.x, Ib[4*q+0], zb[4*q+0], sb[4*q+0]);
      step(20.0f * xv.y, Ib[4*q+1], zb[4*q+1], sb[4*q+1]);
      step(20.0f * xv.z, Ib[4*q+2], zb[4*q+2], sb[4*q+2]);
      step(20.0f * xv.w, Ib[4*q+3], zb[4*q+3], sb[4*q+3]);
    }

    // logits: max over 16 channels, xor-shuffle within 16-lane groups
    float gb[16];
    #pragma unroll
    for (int q = 0; q < 16; ++q) gb[q] = zb[q];
    #pragma unroll
    for (int msk = 1; msk < 16; msk <<= 1) {
      #pragma unroll
      for (int q = 0; q < 16; ++q) gb[q] = fmaxf(gb[q], __shfl_xor(gb[q], msk, 16));
    }

    float4* pI = (float4*)(outI + t);
    float4* pZ = (float4*)(outZ + t);
    float4* pS = (float4*)(outS + t);
    #pragma unroll
    for (int q = 0; q < 4; ++q)
      pI[q] = make_float4(Ib[4*q+0], Ib[4*q+1], Ib[4*q+2], Ib[4*q+3]);
    #pragma unroll
    for (int q = 0; q < 4; ++q)
      pZ[q] = make_float4(zb[4*q+0], zb[4*q+1], zb[4*q+2], zb[4*q+3]);
    #pragma unroll
    for (int q = 0; q < 4; ++q)
      pS[q] = make_float4(sb[4*q+0], sb[4*q+1], sb[4*q+2], sb[4*q+3]);
    if (c16 == 0) {
      float4* pG = (float4*)(outG + t);
      #pragma unroll
      for (int q = 0; q < 4; ++q)
        pG[q] = make_float4(gb[4*q+0], gb[4*q+1], gb[4*q+2], gb[4*q+3]);
    }
  }
}

extern "C" void kernel_launch(void* const* d_in, const int* in_sizes, int n_in,
                              void* d_out, int out_size, void* d_ws, size_t ws_size,
                              hipStream_t stream) {
  const float* x   = (const float*)d_in[0];
  const float* wa  = (const float*)d_in[1];
  const float* wb  = (const float*)d_in[2];
  const float* rta = (const float*)d_in[3];
  const float* rtb = (const float*)d_in[4];
  const float* rga = (const float*)d_in[5];
  const float* rgb = (const float*)d_in[6];
  float* out = (float*)d_out;

  dim3 grid(NTILES, NB);
  hipLaunchKernelGGL(snn_fused, grid, dim3(256), 0, stream,
                     x, wa, wb, rta, rtb, rga, rgb, out);
}